// Round 1
// baseline (541.697 us; speedup 1.0000x reference)
//
#include <hip/hip_runtime.h>
#include <math.h>

#define Bn 64
#define Sn 512
#define Hn 768
#define ATT_H 100
#define CLS_H 300
#define Mtok (Bn*Sn)          // 32768
#define NP 112                // padded ATT_H
#define BM 128
#define BK 32
#define HS_STRIDE 36          // 32 + 4 pad, keeps 16B alignment, breaks bank conflicts

__device__ inline float sigf(float x) { return 1.0f / (1.0f + expf(-x)); }

__device__ inline float wred_sum(float v) {
    #pragma unroll
    for (int d = 32; d; d >>= 1) v += __shfl_down(v, d, 64);
    return v;
}
__device__ inline float wred_max(float v) {
    #pragma unroll
    for (int d = 32; d; d >>= 1) v = fmaxf(v, __shfl_down(v, d, 64));
    return v;
}
__device__ inline float wred_min(float v) {
    #pragma unroll
    for (int d = 32; d; d >>= 1) v = fminf(v, __shfl_down(v, d, 64));
    return v;
}

// ---------------------------------------------------------------------------
// K1: token_att = sigmoid(tanh(h @ W1 + b1) @ W2 + b2), fused with the
// hidden_states -> out passthrough copy (each h element is loaded exactly once
// here, so we store it to out_hidden for free).
// Tiling: 256 blocks x 256 threads; block = 128 tokens, full 100(->112) cols.
// thread (tm = tid>>2, tq = tid&3) owns tokens {tm, tm+64} x cols [tq*28, +28).
// ---------------------------------------------------------------------------
__global__ __launch_bounds__(256) void k1_att(
    const float* __restrict__ h, const float* __restrict__ W1,
    const float* __restrict__ b1, const float* __restrict__ W2,
    const float* __restrict__ b2, float* __restrict__ out_hidden,
    float* __restrict__ att)
{
    __shared__ float hs[BM * HS_STRIDE];   // 18 KB
    __shared__ float wsm[BK * NP];         // 14 KB
    __shared__ float zred[512];            // 2 KB

    const int tid = threadIdx.x;
    const int tq = tid & 3, tm = tid >> 2;
    const int row0 = blockIdx.x * BM + tm;     // second token: row0 + 64
    const int c0 = tq * 28;

    float acc0[28], acc1[28];
    #pragma unroll
    for (int j = 0; j < 28; j++) { acc0[j] = 0.f; acc1[j] = 0.f; }

    for (int k0 = 0; k0 < Hn; k0 += BK) {
        // stage h tile (and emit passthrough copy)
        #pragma unroll
        for (int it = 0; it < 4; it++) {
            int i = tid + it * 256;            // 0..1023
            int r = i >> 3;
            int c4 = (i & 7) * 4;
            size_t gidx = (size_t)(blockIdx.x * BM + r) * Hn + k0 + c4;
            float4 v = *(const float4*)(h + gidx);
            *(float4*)(out_hidden + gidx) = v;
            *(float4*)(&hs[r * HS_STRIDE + c4]) = v;
        }
        // stage W1 chunk, zero-padded to 112 cols
        #pragma unroll
        for (int it = 0; it < 14; it++) {
            int i = tid + it * 256;            // 0..3583
            int kk = i / NP;
            int j = i - kk * NP;
            wsm[i] = (j < ATT_H) ? W1[(size_t)(k0 + kk) * ATT_H + j] : 0.f;
        }
        __syncthreads();

        #pragma unroll
        for (int kk = 0; kk < BK; kk++) {
            float a0 = hs[tm * HS_STRIDE + kk];
            float a1 = hs[(tm + 64) * HS_STRIDE + kk];
            const float* wr = &wsm[kk * NP + c0];
            #pragma unroll
            for (int j4 = 0; j4 < 7; j4++) {
                float4 w = *(const float4*)(wr + j4 * 4);
                acc0[j4*4+0] += a0 * w.x;  acc1[j4*4+0] += a1 * w.x;
                acc0[j4*4+1] += a0 * w.y;  acc1[j4*4+1] += a1 * w.y;
                acc0[j4*4+2] += a0 * w.z;  acc1[j4*4+2] += a1 * w.z;
                acc0[j4*4+3] += a0 * w.w;  acc1[j4*4+3] += a1 * w.w;
            }
        }
        __syncthreads();
    }

    // epilogue: tanh, dot with W2, reduce over the 4 col-groups
    float z0 = 0.f, z1 = 0.f;
    #pragma unroll
    for (int j = 0; j < 28; j++) {
        int col = c0 + j;
        if (col < ATT_H) {
            float w2 = W2[col];
            float bb = b1[col];
            z0 += tanhf(acc0[j] + bb) * w2;
            z1 += tanhf(acc1[j] + bb) * w2;
        }
    }
    zred[tid] = z0;
    zred[256 + tid] = z1;
    __syncthreads();
    if (tq == 0) {
        float bb2 = b2[0];
        int base = tm * 4;
        float zz0 = zred[base] + zred[base+1] + zred[base+2] + zred[base+3] + bb2;
        float zz1 = zred[256+base] + zred[256+base+1] + zred[256+base+2] + zred[256+base+3] + bb2;
        att[row0]      = sigf(zz0);
        att[row0 + 64] = sigf(zz1);
    }
}

// ---------------------------------------------------------------------------
// K2: per batch row — segmented max over subword groups (backward segmented
// max-scan implemented as forward Hillis-Steele on the reversed row), masking,
// and the per-row reductions. One block per batch row.
// ---------------------------------------------------------------------------
__global__ __launch_bounds__(256) void k2_seg(
    const float* __restrict__ att, const int* __restrict__ offset,
    const float* __restrict__ labels, float* __restrict__ masked_out,
    float* __restrict__ sum_m, float* __restrict__ slab_o,
    float* __restrict__ tl_o, float* __restrict__ mino_o,
    float* __restrict__ maxm_o)
{
    const int b = blockIdx.x, tid = threadIdx.x;
    __shared__ float attl[Sn];
    __shared__ int   startl[Sn];
    __shared__ float v0[Sn], v1[Sn];
    __shared__ int   f0[Sn], f1[Sn];
    __shared__ float rsum[4], rtl[4], rsl[4], rmn[4], rmx[4];

    for (int s = tid; s < Sn; s += 256) {
        attl[s] = att[b * Sn + s];
        startl[s] = (offset[(size_t)(b * Sn + s) * 2] == 0) ? 1 : 0;
    }
    __syncthreads();
    // reversed arrays: i = Sn-1-s ; head flag = "s is segment end"
    for (int i = tid; i < Sn; i += 256) {
        int s = Sn - 1 - i;
        int endf = (s == Sn - 1) ? 1 : startl[s + 1];
        v0[i] = attl[s];
        f0[i] = endf;
    }
    __syncthreads();

    float* va = v0; float* vb = v1;
    int* fa = f0; int* fb = f1;
    for (int d = 1; d < Sn; d <<= 1) {
        for (int i = tid; i < Sn; i += 256) {
            float v = va[i]; int f = fa[i];
            float nv = v; int nf = f;
            if (i >= d) {
                if (!f) nv = fmaxf(v, va[i - d]);
                nf = f | fa[i - d];
            }
            vb[i] = nv; fb[i] = nf;
        }
        __syncthreads();
        float* tv = va; va = vb; vb = tv;
        int* tf = fa; fa = fb; fb = tf;
    }

    float lsum = 0.f, ltl = 0.f, lslab = -1e30f, lmin = 1e30f, lmax = -1e30f;
    for (int s = tid; s < Sn; s += 256) {
        float lab = labels[b * Sn + s];
        int st = startl[s];
        float segm = va[Sn - 1 - s];
        float m = (st && lab != -1.0f) ? segm : 0.f;
        masked_out[b * Sn + s] = m;
        lsum += m;
        float zl = (lab == 1.0f) ? 1.f : 0.f;
        ltl += (m - zl) * (m - zl);
        lslab = fmaxf(lslab, lab);
        float om = (m == 0.f) ? 1.f : m;
        lmin = fminf(lmin, om);
        lmax = fmaxf(lmax, m);
    }
    int wid = tid >> 6, lane = tid & 63;
    lsum = wred_sum(lsum); ltl = wred_sum(ltl);
    lslab = wred_max(lslab); lmin = wred_min(lmin); lmax = wred_max(lmax);
    if (lane == 0) { rsum[wid]=lsum; rtl[wid]=ltl; rsl[wid]=lslab; rmn[wid]=lmin; rmx[wid]=lmax; }
    __syncthreads();
    if (tid == 0) {
        sum_m[b]  = rsum[0]+rsum[1]+rsum[2]+rsum[3];
        tl_o[b]   = rtl[0]+rtl[1]+rtl[2]+rtl[3];
        slab_o[b] = fmaxf(fmaxf(rsl[0],rsl[1]), fmaxf(rsl[2],rsl[3]));
        mino_o[b] = fminf(fminf(rmn[0],rmn[1]), fminf(rmn[2],rmn[3]));
        maxm_o[b] = fmaxf(fmaxf(rmx[0],rmx[1]), fmaxf(rmx[2],rmx[3]));
    }
}

// ---------------------------------------------------------------------------
// K3: pooled[b,hd] = sum_s h[b,s,hd] * masked[b,s]/sum_m[b]
// grid (64 b, 3 hd-chunks of 256, 2 s-halves); partial results summed in K4.
// ---------------------------------------------------------------------------
__global__ __launch_bounds__(256) void k3_pool(
    const float* __restrict__ h, const float* __restrict__ masked,
    const float* __restrict__ sum_m, float* __restrict__ pooledp)
{
    const int b = blockIdx.x, cc = blockIdx.y, sh = blockIdx.z;
    const int tid = threadIdx.x;
    __shared__ float nrm[256];
    float inv = 1.0f / sum_m[b];
    int sbase = sh * 256;
    nrm[tid] = masked[b * Sn + sbase + tid] * inv;
    __syncthreads();
    int hd = cc * 256 + tid;
    const float* hp = h + ((size_t)b * Sn + sbase) * Hn + hd;
    float acc = 0.f;
    #pragma unroll 4
    for (int i = 0; i < 256; i++) acc += hp[(size_t)i * Hn] * nrm[i];
    pooledp[((size_t)sh * Bn + b) * Hn + hd] = acc;
}

// ---------------------------------------------------------------------------
// K4: sent[b] = sigmoid(tanh(pooled @ W3 + b3) @ W4 + b4). One block per b.
// ---------------------------------------------------------------------------
__global__ __launch_bounds__(256) void k4_sent(
    const float* __restrict__ pooledp, const float* __restrict__ W3,
    const float* __restrict__ b3, const float* __restrict__ W4,
    const float* __restrict__ b4, float* __restrict__ sent_out)
{
    const int b = blockIdx.x, tid = threadIdx.x;
    __shared__ float pl[Hn];
    __shared__ float red[4];
    for (int k = tid; k < Hn; k += 256)
        pl[k] = pooledp[(size_t)b * Hn + k] + pooledp[(size_t)(Bn + b) * Hn + k];
    __syncthreads();
    int j0 = tid;
    int j1 = tid + 256;
    int j1c = (j1 < CLS_H) ? j1 : (CLS_H - 1);
    float a0 = 0.f, a1 = 0.f;
    for (int k = 0; k < Hn; k++) {
        float p = pl[k];
        a0 += p * W3[(size_t)k * CLS_H + j0];
        a1 += p * W3[(size_t)k * CLS_H + j1c];
    }
    float y = tanhf(a0 + b3[j0]) * W4[j0];
    if (j1 < CLS_H) y += tanhf(a1 + b3[j1]) * W4[j1];
    int wid = tid >> 6, lane = tid & 63;
    y = wred_sum(y);
    if (lane == 0) red[wid] = y;
    __syncthreads();
    if (tid == 0) {
        float z = red[0] + red[1] + red[2] + red[3] + b4[0];
        sent_out[b] = sigf(z);
    }
}

// ---------------------------------------------------------------------------
// K5: final scalars. One wave; b = lane.
// ---------------------------------------------------------------------------
__global__ __launch_bounds__(64) void k5_loss(
    const float* __restrict__ sent, const float* __restrict__ slab,
    const float* __restrict__ tl, const float* __restrict__ mino,
    const float* __restrict__ maxm, float* __restrict__ out)
{
    int t = threadIdx.x;
    float sl = slab[t];
    float e1 = sent[t] - sl; e1 *= e1;
    float e2 = tl[t];
    float e3 = mino[t] * mino[t];
    float mm = maxm[t] - sl;
    float e4 = mm * mm;
    e1 = wred_sum(e1); e2 = wred_sum(e2); e3 = wred_sum(e3); e4 = wred_sum(e4);
    if (t == 0) {
        out[1] = e1;
        out[2] = e2;
        out[3] = e3;
        out[4] = e4;
        out[0] = e1 + e2 + 0.01f * (e3 + e4);
    }
}

extern "C" void kernel_launch(void* const* d_in, const int* in_sizes, int n_in,
                              void* d_out, int out_size, void* d_ws, size_t ws_size,
                              hipStream_t stream) {
    (void)in_sizes; (void)n_in; (void)out_size; (void)ws_size;
    const float* h      = (const float*)d_in[0];
    const int*   offset = (const int*)d_in[1];
    const float* labels = (const float*)d_in[2];
    const float* W1     = (const float*)d_in[3];
    const float* b1     = (const float*)d_in[4];
    const float* W2     = (const float*)d_in[5];
    const float* b2     = (const float*)d_in[6];
    const float* W3     = (const float*)d_in[7];
    const float* b3     = (const float*)d_in[8];
    const float* W4     = (const float*)d_in[9];
    const float* b4     = (const float*)d_in[10];

    float* out        = (float*)d_out;
    float* out_hidden = out + 5;
    float* out_masked = out_hidden + (size_t)Bn * Sn * Hn;   // 25,165,824
    float* out_sent   = out_masked + (size_t)Bn * Sn;        // 32,768

    float* ws      = (float*)d_ws;
    float* att     = ws;                       // 32768
    float* sum_m   = att + Mtok;               // 64
    float* slab    = sum_m + Bn;               // 64
    float* tlb     = slab + Bn;                // 64
    float* mino    = tlb + Bn;                 // 64
    float* maxm    = mino + Bn;                // 64
    float* pooledp = maxm + Bn;                // 2*64*768

    k1_att<<<Mtok / BM, 256, 0, stream>>>(h, W1, b1, W2, b2, out_hidden, att);
    k2_seg<<<Bn, 256, 0, stream>>>(att, offset, labels, out_masked,
                                   sum_m, slab, tlb, mino, maxm);
    k3_pool<<<dim3(Bn, 3, 2), 256, 0, stream>>>(h, out_masked, sum_m, pooledp);
    k4_sent<<<Bn, 256, 0, stream>>>(pooledp, W3, b3, W4, b4, out_sent);
    k5_loss<<<1, 64, 0, stream>>>(out_sent, slab, tlb, mino, maxm, out);
}

// Round 2
// 316.598 us; speedup vs baseline: 1.7110x; 1.7110x over previous
//
#include <hip/hip_runtime.h>
#include <math.h>

#define Bn 64
#define Sn 512
#define Hn 768
#define ATT_H 100
#define CLS_H 300
#define Mtok (Bn*Sn)          // 32768
#define NP 112                // padded ATT_H (7 x 16)
#define NT 7                  // col tiles of 16

// k1 tiling
#define BM1 64                // tokens per block
#define BK1 128               // k-chunk
#define LDA 136               // BK1 + 8 pad (bf16 elems); row stride 272 B (16B-aligned)

typedef __attribute__((ext_vector_type(8))) short short8;
typedef __attribute__((ext_vector_type(4))) float floatx4;

__device__ inline float sigf(float x) { return 1.0f / (1.0f + expf(-x)); }

__device__ inline unsigned short f2bf(float x) {
    union { float f; unsigned int u; } v; v.f = x;
    unsigned int r = (v.u + 0x7FFFu + ((v.u >> 16) & 1u)) >> 16;
    return (unsigned short)r;
}

__device__ inline float wred_sum(float v) {
    #pragma unroll
    for (int d = 32; d; d >>= 1) v += __shfl_down(v, d, 64);
    return v;
}
__device__ inline float wred_max(float v) {
    #pragma unroll
    for (int d = 32; d; d >>= 1) v = fmaxf(v, __shfl_down(v, d, 64));
    return v;
}
__device__ inline float wred_min(float v) {
    #pragma unroll
    for (int d = 32; d; d >>= 1) v = fminf(v, __shfl_down(v, d, 64));
    return v;
}

// ---------------------------------------------------------------------------
// K0: prep. W1T[n][k] = bf16(W1[k][n]) for n<100 else 0  (112 x 768 bf16),
// and b1w2[n] = (b1[n], W2[n]) zero-padded to 112 (float2).
// ---------------------------------------------------------------------------
__global__ __launch_bounds__(256) void k0_prep(
    const float* __restrict__ W1, const float* __restrict__ b1,
    const float* __restrict__ W2, unsigned short* __restrict__ w1t,
    float* __restrict__ b1w2)
{
    int idx = blockIdx.x * 256 + threadIdx.x;
    if (idx < NP * Hn) {
        int n = idx / Hn;
        int k = idx - n * Hn;
        float v = (n < ATT_H) ? W1[(size_t)k * ATT_H + n] : 0.f;
        w1t[(size_t)n * Hn + k] = f2bf(v);
    } else {
        int j = idx - NP * Hn;
        if (j < NP) {
            b1w2[2 * j]     = (j < ATT_H) ? b1[j] : 0.f;
            b1w2[2 * j + 1] = (j < ATT_H) ? W2[j] : 0.f;
        }
    }
}

// ---------------------------------------------------------------------------
// K1: token_att = sigmoid(tanh(h @ W1 + b1) @ W2 + b2) via bf16 MFMA,
// fused with the hidden_states passthrough copy.
// 512 blocks x 256 threads (4 waves). Block = 64 tokens; wave = 16-token
// row-tile x 7 col-tiles. A (h, bf16) staged via LDS; B (W1T) frags read
// from global (L1-resident: all 4 waves read the same 28KB chunk).
// MFMA 16x16x32 bf16: A[m=lane&15][k=(lane>>4)*8+j]; B[k][n=lane&15];
// D col=lane&15, row=(lane>>4)*4+reg.
// ---------------------------------------------------------------------------
__global__ __launch_bounds__(256) void k1_att(
    const float* __restrict__ h, const unsigned short* __restrict__ w1t,
    const float* __restrict__ b1w2, const float* __restrict__ b2,
    float* __restrict__ out_hidden, float* __restrict__ att)
{
    __shared__ unsigned short As[BM1 * LDA];   // 17408 B

    const int tid = threadIdx.x;
    const int wave = tid >> 6, lane = tid & 63;
    const int u = lane & 15, q = lane >> 4;
    const int t0 = blockIdx.x * BM1;

    floatx4 acc[NT];
    #pragma unroll
    for (int ct = 0; ct < NT; ct++) acc[ct] = (floatx4)0.f;

    for (int k0 = 0; k0 < Hn; k0 += BK1) {
        __syncthreads();
        // stage 64 tokens x 128 k: fp32 read + passthrough store + bf16->LDS
        #pragma unroll
        for (int it = 0; it < 8; it++) {
            int idx = it * 256 + tid;            // 0..2047 float4 slots
            int m = idx >> 5;                    // 0..63
            int c4 = (idx & 31) * 4;             // 0..124
            size_t g = (size_t)(t0 + m) * Hn + k0 + c4;
            float4 v = *(const float4*)(h + g);
            *(float4*)(out_hidden + g) = v;
            ushort4 bv;
            bv.x = f2bf(v.x); bv.y = f2bf(v.y);
            bv.z = f2bf(v.z); bv.w = f2bf(v.w);
            *(ushort4*)(&As[m * LDA + c4]) = bv;
        }
        __syncthreads();

        #pragma unroll
        for (int kk = 0; kk < BK1 / 32; kk++) {
            short8 a = *(const short8*)(&As[(wave * 16 + u) * LDA + kk * 32 + q * 8]);
            #pragma unroll
            for (int ct = 0; ct < NT; ct++) {
                const short8* bp = (const short8*)(w1t + (size_t)(ct * 16 + u) * Hn
                                                   + k0 + kk * 32 + q * 8);
                acc[ct] = __builtin_amdgcn_mfma_f32_16x16x32_bf16(a, *bp, acc[ct], 0, 0, 0);
            }
        }
    }

    // epilogue: z[token] = sum_n tanh(D[token][n] + b1[n]) * W2[n]
    float z[4] = {0.f, 0.f, 0.f, 0.f};
    #pragma unroll
    for (int ct = 0; ct < NT; ct++) {
        float2 bw = *(const float2*)(b1w2 + (ct * 16 + u) * 2);
        #pragma unroll
        for (int r = 0; r < 4; r++)
            z[r] += tanhf(acc[ct][r] + bw.x) * bw.y;
    }
    #pragma unroll
    for (int mask = 1; mask < 16; mask <<= 1) {
        #pragma unroll
        for (int r = 0; r < 4; r++) z[r] += __shfl_xor(z[r], mask, 64);
    }
    if (u == 0) {
        float bb2 = b2[0];
        #pragma unroll
        for (int r = 0; r < 4; r++)
            att[t0 + wave * 16 + q * 4 + r] = sigf(z[r] + bb2);
    }
}

// ---------------------------------------------------------------------------
// K2: per batch row — segmented max (reversed Hillis-Steele), masking,
// per-row reductions. One block per batch row.
// ---------------------------------------------------------------------------
__global__ __launch_bounds__(256) void k2_seg(
    const float* __restrict__ att, const int* __restrict__ offset,
    const float* __restrict__ labels, float* __restrict__ masked_out,
    float* __restrict__ sum_m, float* __restrict__ slab_o,
    float* __restrict__ tl_o, float* __restrict__ mino_o,
    float* __restrict__ maxm_o)
{
    const int b = blockIdx.x, tid = threadIdx.x;
    __shared__ float attl[Sn];
    __shared__ int   startl[Sn];
    __shared__ float v0[Sn], v1[Sn];
    __shared__ int   f0[Sn], f1[Sn];
    __shared__ float rsum[4], rtl[4], rsl[4], rmn[4], rmx[4];

    for (int s = tid; s < Sn; s += 256) {
        attl[s] = att[b * Sn + s];
        startl[s] = (offset[(size_t)(b * Sn + s) * 2] == 0) ? 1 : 0;
    }
    __syncthreads();
    for (int i = tid; i < Sn; i += 256) {
        int s = Sn - 1 - i;
        int endf = (s == Sn - 1) ? 1 : startl[s + 1];
        v0[i] = attl[s];
        f0[i] = endf;
    }
    __syncthreads();

    float* va = v0; float* vb = v1;
    int* fa = f0; int* fb = f1;
    for (int d = 1; d < Sn; d <<= 1) {
        for (int i = tid; i < Sn; i += 256) {
            float v = va[i]; int f = fa[i];
            float nv = v; int nf = f;
            if (i >= d) {
                if (!f) nv = fmaxf(v, va[i - d]);
                nf = f | fa[i - d];
            }
            vb[i] = nv; fb[i] = nf;
        }
        __syncthreads();
        float* tv = va; va = vb; vb = tv;
        int* tf = fa; fa = fb; fb = tf;
    }

    float lsum = 0.f, ltl = 0.f, lslab = -1e30f, lmin = 1e30f, lmax = -1e30f;
    for (int s = tid; s < Sn; s += 256) {
        float lab = labels[b * Sn + s];
        int st = startl[s];
        float segm = va[Sn - 1 - s];
        float m = (st && lab != -1.0f) ? segm : 0.f;
        masked_out[b * Sn + s] = m;
        lsum += m;
        float zl = (lab == 1.0f) ? 1.f : 0.f;
        ltl += (m - zl) * (m - zl);
        lslab = fmaxf(lslab, lab);
        float om = (m == 0.f) ? 1.f : m;
        lmin = fminf(lmin, om);
        lmax = fmaxf(lmax, m);
    }
    int wid = tid >> 6, lane = tid & 63;
    lsum = wred_sum(lsum); ltl = wred_sum(ltl);
    lslab = wred_max(lslab); lmin = wred_min(lmin); lmax = wred_max(lmax);
    if (lane == 0) { rsum[wid]=lsum; rtl[wid]=ltl; rsl[wid]=lslab; rmn[wid]=lmin; rmx[wid]=lmax; }
    __syncthreads();
    if (tid == 0) {
        sum_m[b]  = rsum[0]+rsum[1]+rsum[2]+rsum[3];
        tl_o[b]   = rtl[0]+rtl[1]+rtl[2]+rtl[3];
        slab_o[b] = fmaxf(fmaxf(rsl[0],rsl[1]), fmaxf(rsl[2],rsl[3]));
        mino_o[b] = fminf(fminf(rmn[0],rmn[1]), fminf(rmn[2],rmn[3]));
        maxm_o[b] = fmaxf(fmaxf(rmx[0],rmx[1]), fmaxf(rmx[2],rmx[3]));
    }
}

// ---------------------------------------------------------------------------
// K3: pooled partials. grid (64 b, 8 s-chunks), 192 threads; thread owns one
// float4 column group across 64 s rows (fully coalesced 3KB/row reads).
// ---------------------------------------------------------------------------
__global__ __launch_bounds__(192) void k3_pool(
    const float* __restrict__ h, const float* __restrict__ masked,
    const float* __restrict__ sum_m, float* __restrict__ pooledp)
{
    const int b = blockIdx.x, sc = blockIdx.y;
    const int tid = threadIdx.x;
    __shared__ float nrm[64];
    if (tid < 64)
        nrm[tid] = masked[b * Sn + sc * 64 + tid] * (1.0f / sum_m[b]);
    __syncthreads();
    const float4* hp = (const float4*)(h + ((size_t)b * Sn + sc * 64) * Hn) + tid;
    float ax = 0.f, ay = 0.f, az = 0.f, aw = 0.f;
    #pragma unroll 4
    for (int s = 0; s < 64; s++) {
        float4 v = hp[(size_t)s * (Hn / 4)];
        float w = nrm[s];
        ax += v.x * w; ay += v.y * w; az += v.z * w; aw += v.w * w;
    }
    float4 r; r.x = ax; r.y = ay; r.z = az; r.w = aw;
    ((float4*)(pooledp + ((size_t)(sc * Bn + b)) * Hn))[tid] = r;
}

// ---------------------------------------------------------------------------
// K4: sent[b] = sigmoid(tanh(pooled @ W3 + b3) @ W4 + b4). One block per b.
// ---------------------------------------------------------------------------
__global__ __launch_bounds__(256) void k4_sent(
    const float* __restrict__ pooledp, const float* __restrict__ W3,
    const float* __restrict__ b3, const float* __restrict__ W4,
    const float* __restrict__ b4, float* __restrict__ sent_out)
{
    const int b = blockIdx.x, tid = threadIdx.x;
    __shared__ float pl[Hn];
    __shared__ float red[4];
    for (int k = tid; k < Hn; k += 256) {
        float acc = 0.f;
        #pragma unroll
        for (int sc = 0; sc < 8; sc++)
            acc += pooledp[((size_t)(sc * Bn + b)) * Hn + k];
        pl[k] = acc;
    }
    __syncthreads();
    int j0 = tid;
    int j1 = tid + 256;
    int j1c = (j1 < CLS_H) ? j1 : (CLS_H - 1);
    float a0 = 0.f, a1 = 0.f;
    for (int k = 0; k < Hn; k++) {
        float p = pl[k];
        a0 += p * W3[(size_t)k * CLS_H + j0];
        a1 += p * W3[(size_t)k * CLS_H + j1c];
    }
    float y = tanhf(a0 + b3[j0]) * W4[j0];
    if (j1 < CLS_H) y += tanhf(a1 + b3[j1]) * W4[j1];
    int wid = tid >> 6, lane = tid & 63;
    y = wred_sum(y);
    if (lane == 0) red[wid] = y;
    __syncthreads();
    if (tid == 0) {
        float z = red[0] + red[1] + red[2] + red[3] + b4[0];
        sent_out[b] = sigf(z);
    }
}

// ---------------------------------------------------------------------------
// K5: final scalars. One wave; b = lane.
// ---------------------------------------------------------------------------
__global__ __launch_bounds__(64) void k5_loss(
    const float* __restrict__ sent, const float* __restrict__ slab,
    const float* __restrict__ tl, const float* __restrict__ mino,
    const float* __restrict__ maxm, float* __restrict__ out)
{
    int t = threadIdx.x;
    float sl = slab[t];
    float e1 = sent[t] - sl; e1 *= e1;
    float e2 = tl[t];
    float e3 = mino[t] * mino[t];
    float mm = maxm[t] - sl;
    float e4 = mm * mm;
    e1 = wred_sum(e1); e2 = wred_sum(e2); e3 = wred_sum(e3); e4 = wred_sum(e4);
    if (t == 0) {
        out[1] = e1;
        out[2] = e2;
        out[3] = e3;
        out[4] = e4;
        out[0] = e1 + e2 + 0.01f * (e3 + e4);
    }
}

extern "C" void kernel_launch(void* const* d_in, const int* in_sizes, int n_in,
                              void* d_out, int out_size, void* d_ws, size_t ws_size,
                              hipStream_t stream) {
    (void)in_sizes; (void)n_in; (void)out_size; (void)ws_size;
    const float* h      = (const float*)d_in[0];
    const int*   offset = (const int*)d_in[1];
    const float* labels = (const float*)d_in[2];
    const float* W1     = (const float*)d_in[3];
    const float* b1     = (const float*)d_in[4];
    const float* W2     = (const float*)d_in[5];
    const float* b2     = (const float*)d_in[6];
    const float* W3     = (const float*)d_in[7];
    const float* b3     = (const float*)d_in[8];
    const float* W4     = (const float*)d_in[9];
    const float* b4     = (const float*)d_in[10];

    float* out        = (float*)d_out;
    float* out_hidden = out + 5;
    float* out_masked = out_hidden + (size_t)Bn * Sn * Hn;   // 25,165,824
    float* out_sent   = out_masked + (size_t)Bn * Sn;        // 32,768

    float* ws      = (float*)d_ws;
    float* att     = ws;                       // 32768
    float* sum_m   = att + Mtok;               // 64
    float* slab    = sum_m + Bn;               // 64
    float* tlb     = slab + Bn;                // 64
    float* mino    = tlb + Bn;                 // 64
    float* maxm    = mino + Bn;                // 64
    float* pooledp = maxm + Bn;                // 8*64*768 = 393216
    unsigned short* w1t = (unsigned short*)(pooledp + 8 * Bn * Hn);  // 112*768 bf16
    float* b1w2    = (float*)(w1t + (size_t)NP * Hn);                // 224 floats

    k0_prep<<<(NP * Hn + NP + 255) / 256, 256, 0, stream>>>(W1, b1, W2, w1t, b1w2);
    k1_att<<<Mtok / BM1, 256, 0, stream>>>(h, w1t, b1w2, b2, out_hidden, att);
    k2_seg<<<Bn, 256, 0, stream>>>(att, offset, labels, out_masked,
                                   sum_m, slab, tlb, mino, maxm);
    k3_pool<<<dim3(Bn, 8), 192, 0, stream>>>(h, out_masked, sum_m, pooledp);
    k4_sent<<<Bn, 256, 0, stream>>>(pooledp, W3, b3, W4, b4, out_sent);
    k5_loss<<<1, 64, 0, stream>>>(out_sent, slab, tlb, mino, maxm, out);
}